// Round 1
// baseline (324.649 us; speedup 1.0000x reference)
//
#include <hip/hip_runtime.h>

#define HM 64
#define MID 10

__device__ __forceinline__ float clip01(float v) {
    return fminf(fmaxf(v, 0.0f), 1.0f);
}

__global__ __launch_bounds__(256) void gotd_kernel(
    const float* __restrict__ gaze,
    const float* __restrict__ head,
    const float* __restrict__ conn,
    const float* __restrict__ watch,
    float* __restrict__ out,
    int n_elems)
{
    const int wid  = (int)((blockIdx.x * blockDim.x + threadIdx.x) >> 6);
    const int lane = (int)(threadIdx.x & 63);
    if (wid >= n_elems) return;

    const size_t base = (size_t)wid * (HM * HM);
    const float4* h4 = reinterpret_cast<const float4*>(head + base);
    const float4* g4 = reinterpret_cast<const float4*>(gaze + base);
    const float*  cp = conn + base;

    // ---------------- head pass: global argmax (first occurrence, clipped)
    // + 64-bit row-any / col-any masks for the >=0.5 threshold ----------------
    float hbest = -1.0f; int hidx = 0;
    unsigned long long rowbits = 0ULL;
    unsigned long long colbits = 0ULL;   // per-lane partial, OR-reduced later
    const int c0 = (lane & 15) * 4;      // this lane's 4 columns
    #pragma unroll
    for (int j = 0; j < 16; ++j) {
        float4 v = h4[j * 64 + lane];
        const int flat = j * 256 + lane * 4;   // row = flat/64, col = flat%64
        float a0 = clip01(v.x), a1 = clip01(v.y), a2 = clip01(v.z), a3 = clip01(v.w);
        if (a0 > hbest) { hbest = a0; hidx = flat + 0; }
        if (a1 > hbest) { hbest = a1; hidx = flat + 1; }
        if (a2 > hbest) { hbest = a2; hidx = flat + 2; }
        if (a3 > hbest) { hbest = a3; hidx = flat + 3; }
        unsigned m4 = (a0 >= 0.5f ? 1u : 0u) | (a1 >= 0.5f ? 2u : 0u)
                    | (a2 >= 0.5f ? 4u : 0u) | (a3 >= 0.5f ? 8u : 0u);
        colbits |= (unsigned long long)m4 << c0;
        // row of this lane's 4 elements: j*4 + (lane>>4); 16 lanes per row
        unsigned long long bal = __ballot(m4 != 0u);
        const int rbase = j * 4;
        if ( bal        & 0xFFFFULL) rowbits |= 1ULL << (rbase + 0);
        if ((bal >> 16) & 0xFFFFULL) rowbits |= 1ULL << (rbase + 1);
        if ((bal >> 32) & 0xFFFFULL) rowbits |= 1ULL << (rbase + 2);
        if ((bal >> 48) & 0xFFFFULL) rowbits |= 1ULL << (rbase + 3);
    }
    // OR-reduce colbits across lanes (wave-uniform result), 32-bit halves
    {
        unsigned lo = (unsigned)colbits, hi = (unsigned)(colbits >> 32);
        #pragma unroll
        for (int off = 32; off >= 1; off >>= 1) {
            lo |= __shfl_xor(lo, off);
            hi |= __shfl_xor(hi, off);
        }
        colbits = ((unsigned long long)hi << 32) | lo;
    }
    // argmax reduce (tie -> smaller flat index = first occurrence)
    #pragma unroll
    for (int off = 32; off >= 1; off >>= 1) {
        float ov = __shfl_xor(hbest, off);
        int   oi = __shfl_xor(hidx, off);
        if (ov > hbest || (ov == hbest && oi < hidx)) { hbest = ov; hidx = oi; }
    }
    const float conf_head = hbest;  // == max over region (see analysis)

    int x1, x2, y1, y2;
    if (colbits != 0ULL) {
        x1 = __builtin_ctzll(colbits);
        x2 = 64 - __builtin_clzll(colbits);
        y1 = __builtin_ctzll(rowbits);
        y2 = 64 - __builtin_clzll(rowbits);
    } else {
        const int px = hidx & 63, py = hidx >> 6;
        x1 = px; x2 = px + 1; y1 = py; y2 = py + 1;
    }
    const float cx = (float)(x1 + x2) * 0.5f;
    const float cy = (float)(y1 + y2) * 0.5f;

    // ---------------- gaze pass: global argmax (first occurrence, clipped) --
    float gbest = -1.0f; int gidx = 0;
    #pragma unroll
    for (int j = 0; j < 16; ++j) {
        float4 v = g4[j * 64 + lane];
        const int flat = j * 256 + lane * 4;
        float a0 = clip01(v.x), a1 = clip01(v.y), a2 = clip01(v.z), a3 = clip01(v.w);
        if (a0 > gbest) { gbest = a0; gidx = flat + 0; }
        if (a1 > gbest) { gbest = a1; gidx = flat + 1; }
        if (a2 > gbest) { gbest = a2; gidx = flat + 2; }
        if (a3 > gbest) { gbest = a3; gidx = flat + 3; }
    }
    #pragma unroll
    for (int off = 32; off >= 1; off >>= 1) {
        float ov = __shfl_xor(gbest, off);
        int   oi = __shfl_xor(gidx, off);
        if (ov > gbest || (ov == gbest && oi < gidx)) { gbest = ov; gidx = oi; }
    }
    const float conf_gaze = gbest;
    const int gx = gidx & 63, gy = gidx >> 6;

    // ---------------- connect line sampling (lanes 0..9) --------------------
    const float gpx = (float)gx, gpy = (float)gy;                 // in [0,63]
    const float hcx = fminf(fmaxf(rintf(cx), 0.0f), 63.0f);       // round-half-even
    const float hcy = fminf(fmaxf(rintf(cy), 0.0f), 63.0f);
    const float stpx = (gpx - hcx) / 9.0f;   // linspace step, num=10
    const float stpy = (gpy - hcy) / 9.0f;

    float s = 0.0f;
    if (lane < MID) {
        const float sx = hcx + (float)lane * stpx;
        const float sy = hcy + (float)lane * stpy;
        const int xi = (int)rintf(sx);
        const int yi = (int)rintf(sy);
        s = clip01(cp[yi * HM + xi]);
    }
    #pragma unroll
    for (int off = 32; off >= 1; off >>= 1) s += __shfl_xor(s, off);

    const float vx = gpx - hcx, vy = gpy - hcy;
    const float norm = sqrtf(vx * vx + vy * vy);
    const float dist_prior = fminf(32.0f / norm - 1.0f, 0.0f);  // norm=0 -> inf -> 0
    const float swdp = s / 10.0f + dist_prior;

    const float w = watch[wid];
    const float score = (w > 0.5f)
        ? (conf_head + (1.0f - conf_gaze) - swdp) / 3.0f
        : (conf_head + conf_gaze + swdp) / 3.0f;

    if (lane == 0) out[wid] = score;
}

extern "C" void kernel_launch(void* const* d_in, const int* in_sizes, int n_in,
                              void* d_out, int out_size, void* d_ws, size_t ws_size,
                              hipStream_t stream) {
    const float* gaze  = (const float*)d_in[0];
    const float* head  = (const float*)d_in[1];
    const float* conn  = (const float*)d_in[2];
    const float* watch = (const float*)d_in[3];
    float* out = (float*)d_out;
    const int n = in_sizes[3];               // B*Q elements (one score each)
    const int blocks = (n + 3) / 4;          // 4 waves (elements) per 256-thr block
    gotd_kernel<<<blocks, 256, 0, stream>>>(gaze, head, conn, watch, out, n);
}